// Round 7
// baseline (213.032 us; speedup 1.0000x reference)
//
#include <hip/hip_runtime.h>
#include <stdint.h>

#define VOCABN 64
#define EMBN   128
#define HDIM   256
#define NUMIN  7
#define BN     64
#define SN     2048
#define TWOH   512
#define SEG    16
#define SEGLEN 128

#define CZ 2.8853900818f   // 2*log2(e)
#define CF 1.4426950409f   // log2(e)

__device__ __forceinline__ float rcpf(float x){ return __builtin_amdgcn_rcpf(x); }

__device__ __forceinline__ float fast_exp2(float x){
#if __has_builtin(__builtin_amdgcn_exp2f)
    return __builtin_amdgcn_exp2f(x);
#else
    return exp2f(x);
#endif
}

// v_pk_fma_f32 with src0 = SGPR pair, broadcasting its LO word to both lanes of the result
__device__ __forceinline__ float2 pk_fma_s_lo(uint64_t a, float2 b, float2 c){
    float2 d;
    asm("v_pk_fma_f32 %0, %1, %2, %3 op_sel_hi:[0,1,1]" : "=v"(d) : "s"(a), "v"(b), "v"(c));
    return d;
}
// v_pk_fma_f32 with src0 = SGPR pair, broadcasting its HI word
__device__ __forceinline__ float2 pk_fma_s_hi(uint64_t a, float2 b, float2 c){
    float2 d;
    asm("v_pk_fma_f32 %0, %1, %2, %3 op_sel:[1,0,0] op_sel_hi:[1,1,1]" : "=v"(d) : "s"(a), "v"(b), "v"(c));
    return d;
}

// 64-lane sum via DPP; result valid in lane 63.
__device__ __forceinline__ float waveRedDpp(float x){
    x += __int_as_float(__builtin_amdgcn_update_dpp(0, __float_as_int(x), 0x111, 0xf, 0xf, false)); // row_shr:1
    x += __int_as_float(__builtin_amdgcn_update_dpp(0, __float_as_int(x), 0x112, 0xf, 0xf, false)); // row_shr:2
    x += __int_as_float(__builtin_amdgcn_update_dpp(0, __float_as_int(x), 0x114, 0xf, 0xf, false)); // row_shr:4
    x += __int_as_float(__builtin_amdgcn_update_dpp(0, __float_as_int(x), 0x118, 0xf, 0xf, false)); // row_shr:8
    x += __int_as_float(__builtin_amdgcn_update_dpp(0, __float_as_int(x), 0x142, 0xa, 0xf, false)); // row_bcast:15
    x += __int_as_float(__builtin_amdgcn_update_dpp(0, __float_as_int(x), 0x143, 0xc, 0xf, false)); // row_bcast:31
    return x;
}

// ---------------- K0: prepack X rows for scalar loads ----------------
// X'[row] = [n0 n1 n2 n3 n4 n5 n6 evByteOffsetBits]
__global__ __launch_bounds__(256) void k0_prep(const float* __restrict__ X, float* __restrict__ Xp)
{
    const int r = blockIdx.x*256 + threadIdx.x;     // r < BN*SN
    const float4* src = (const float4*)(X + (size_t)r*8);
    const float4 a = src[0], b4 = src[1];
    float4* dst = (float4*)(Xp + (size_t)r*8);
    dst[0] = make_float4(a.y, a.z, a.w, b4.x);
    dst[1] = make_float4(b4.y, b4.z, b4.w, __int_as_float((int)a.x * (HDIM*8)));
}

// ---------------- K1: fold emb/bias/num path into INTERLEAVED, PRE-SCALED tables ----------------
// T[(dir,v,j)] = float2(CZ*z-col j, CF*f-col j); U likewise (so exp2 applies directly).
__global__ __launch_bounds__(512) void k1_tables(
    const float* __restrict__ emb, const float* __restrict__ num_W, const float* __restrict__ num_b,
    const float* __restrict__ Wf, const float* __restrict__ bf,
    const float* __restrict__ Wb, const float* __restrict__ bb,
    float* __restrict__ T, float* __restrict__ U)
{
    const int blk = blockIdx.x;
    const int c = threadIdx.x;
    const int j = c & (HDIM-1);
    const int g = c >> 8;               // 0 -> z gate, 1 -> f gate
    const int col = g*HDIM + j;
    const float gs = g ? CF : CZ;
    if (blk < 2*VOCABN) {
        const int dir = blk & 1, v = blk >> 1;
        const float* W    = dir ? Wb : Wf;
        const float* bias = dir ? bb : bf;
        float acc = bias[col];
        const float* e = emb + (size_t)v*EMBN;
        #pragma unroll 8
        for (int k=0;k<EMBN;++k) acc = fmaf(e[k], W[(size_t)k*768 + col], acc);
        #pragma unroll
        for (int m=0;m<4;++m)    acc = fmaf(num_b[m], W[(size_t)(EMBN+m)*768 + col], acc);
        T[(((size_t)dir*VOCABN + v)*HDIM + j)*2 + g] = acc * gs;
    } else {
        const int dir = blk - 2*VOCABN;
        const float* W = dir ? Wb : Wf;
        #pragma unroll
        for (int i=0;i<NUMIN;++i){
            float acc = 0.f;
            #pragma unroll
            for (int m=0;m<4;++m) acc = fmaf(num_W[i*4+m], W[(size_t)(EMBN+m)*768 + col], acc);
            U[(((size_t)dir*8 + i)*HDIM + j)*2 + g] = acc * gs;
        }
    }
}

// ---------------- K2: segmented fo-pool scan (scalar-fed, LDS-free) ----------------
// MODE 0: per-segment affine coefficients a=prod(f), c=scan from 0.
// MODE 1: scan from hstart, per-wave score partials via DPP reduce.
// MODE 2: scan from hstart, ctx += w[s]*h.
// Block=(b,dir,seg), thread j owns channel j. All per-step shared data (X rows,
// softmax weights) arrives via scalar loads; T rows via saddr-form vector loads
// with a 3-step register prefetch ring. No LDS, no barriers.
template<int MODE>
__global__ __launch_bounds__(256) void k2_scan(
    const float* __restrict__ Xp, const float* __restrict__ T, const float* __restrict__ U,
    const float* __restrict__ Mu, const float* __restrict__ w,
    const float* __restrict__ hstart,
    float* __restrict__ aArr, float* __restrict__ cArr,
    float* __restrict__ swp, float* __restrict__ ctxp)
{
    const int bid = blockIdx.x;
    const int seg = bid & (SEG-1);
    const int dir = (bid >> 4) & 1;
    const int b   = bid >> 5;
    const int j   = threadIdx.x;
    const size_t segIdx = ((size_t)(b*2+dir)*SEG + seg)*HDIM + j;

    const float2* Td2 = (const float2*)T + (size_t)dir*VOCABN*HDIM;
    const float2* Ud2 = (const float2*)U + (size_t)dir*8*HDIM;
    float2 u0 = Ud2[0*HDIM+j], u1 = Ud2[1*HDIM+j], u2 = Ud2[2*HDIM+j],
           u3 = Ud2[3*HDIM+j], u4 = Ud2[4*HDIM+j], u5 = Ud2[5*HDIM+j],
           u6 = Ud2[6*HDIM+j];
    const float mu = (MODE==1) ? Mu[dir*HDIM + j] : 0.f;

    const int sBeg = seg*SEGLEN;
    const int r0   = b*SN + (dir ? (SN-1-sBeg) : sBeg);
    const int dstep= dir ? -1 : 1;
    const uint64_t* xq = (const uint64_t*)Xp;      // 4 qwords per row
    const float* wb = w + (size_t)b*SN + sBeg;     // MODE2 weights (uniform loads)
    const char* Tb = (const char*)Td2;
    const int j8 = j*8;

    #define ROWQ(si,k) (xq[(size_t)(r0 + dstep*(si))*4 + (k)])

    // prologue: row 0 regs + 3-deep T prefetch ring
    uint64_t q0 = ROWQ(0,0), q1 = ROWQ(0,1), q2 = ROWQ(0,2), q3 = ROWQ(0,3);
    float2 tc0 = *(const float2*)(Tb + (int)(q3>>32) + j8);
    float2 tc1 = *(const float2*)(Tb + (int)(ROWQ(1,3)>>32) + j8);
    float2 tc2 = *(const float2*)(Tb + (int)(ROWQ(2,3)>>32) + j8);

    float h = (MODE==0) ? 0.f : hstart[segIdx];
    float aacc = 1.f;
    float ctxacc = 0.f;
    float* swpp = swp + (size_t)(b*8 + dir*4 + (j>>6))*SN + sBeg;

    #pragma unroll 8
    for (int si=0; si<SEGLEN; ++si){
        // scalar prefetch: next row's qwords, and T-row address 3 steps ahead
        const int sn1 = (si+1 < SEGLEN) ? si+1 : SEGLEN-1;
        const uint64_t nq0 = ROWQ(sn1,0), nq1 = ROWQ(sn1,1),
                       nq2 = ROWQ(sn1,2), nq3 = ROWQ(sn1,3);
        const int pf = (si+3 < SEGLEN) ? si+3 : SEGLEN-1;
        const uint64_t pq3 = ROWQ(pf,3);
        const float2 t3 = *(const float2*)(Tb + (int)(pq3>>32) + j8);

        float2 zf = tc0;
        zf = pk_fma_s_lo(q0, u0, zf);   // n0
        zf = pk_fma_s_hi(q0, u1, zf);   // n1
        zf = pk_fma_s_lo(q1, u2, zf);   // n2
        zf = pk_fma_s_hi(q1, u3, zf);   // n3
        zf = pk_fma_s_lo(q2, u4, zf);   // n4
        zf = pk_fma_s_hi(q2, u5, zf);   // n5
        zf = pk_fma_s_lo(q3, u6, zf);   // n6

        // gates via one reciprocal: zf = (CZ*zp, CF*fp) already scaled
        const float e2z = fast_exp2(zf.x);            // e^{2zp}
        const float ef  = fast_exp2(zf.y);            // e^{fp}
        const float a2  = 1.f + e2z;
        const float a1f = 1.f + ef;
        const float r_  = rcpf(a1f * a2);
        const float num = fmaf(ef * h, a2, e2z - 1.f);
        h = num * r_;

        if (MODE==0){
            aacc *= ef * a2 * r_;                     // f = ef/(1+ef)
        } else if (MODE==1){
            float pr = waveRedDpp(h*mu);
            if ((j & 63) == 63) swpp[si] = pr;
        } else {
            ctxacc = fmaf(wb[si], h, ctxacc);
        }
        q0=nq0; q1=nq1; q2=nq2; q3=nq3;
        tc0=tc1; tc1=tc2; tc2=t3;
    }
    #undef ROWQ
    if (MODE==0){ aArr[segIdx] = aacc; cArr[segIdx] = h; }
    if (MODE==2){ ctxp[segIdx] = ctxacc; }
}

// ---------------- compose: hstart[seg] = h; h = a*h + c ----------------
__global__ __launch_bounds__(256) void k_compose(const float* __restrict__ aArr, const float* __restrict__ cArr,
                                                 float* __restrict__ hstart)
{
    const int bd = blockIdx.x;   // b*2 + dir
    const int j  = threadIdx.x;
    float h = 0.f;
    #pragma unroll
    for (int seg=0; seg<SEG; ++seg){
        const size_t idx = ((size_t)bd*SEG + seg)*HDIM + j;
        hstart[idx] = h;
        h = fmaf(aArr[idx], h, cArr[idx]);
    }
}

// ---------------- K3: softmax over S per batch ----------------
__global__ __launch_bounds__(256) void k3_softmax(const float* __restrict__ swp, float* __restrict__ w)
{
    __shared__ float sc[SN];
    __shared__ float red[4];
    const int b = blockIdx.x, t = threadIdx.x;
    for (int s=t; s<SN; s+=256){
        float acc = 0.f;
        #pragma unroll
        for (int r=0;r<8;++r) acc += swp[((size_t)b*8 + r)*SN + s];
        sc[s] = acc;
    }
    __syncthreads();
    float m = -3.4e38f;
    for (int s=t; s<SN; s+=256) m = fmaxf(m, sc[s]);
    #pragma unroll
    for (int o=32;o;o>>=1) m = fmaxf(m, __shfl_xor(m,o,64));
    if ((t&63)==0) red[t>>6] = m;
    __syncthreads();
    m = fmaxf(fmaxf(red[0],red[1]), fmaxf(red[2],red[3]));
    float zs = 0.f;
    for (int s=t; s<SN; s+=256){
        float e = __expf(sc[s]-m);
        sc[s] = e;
        zs += e;
    }
    #pragma unroll
    for (int o=32;o;o>>=1) zs += __shfl_xor(zs,o,64);
    __syncthreads();
    if ((t&63)==0) red[t>>6] = zs;
    __syncthreads();
    zs = red[0]+red[1]+red[2]+red[3];
    float invz = rcpf(zs);
    for (int s=t; s<SN; s+=256) w[(size_t)b*SN + s] = sc[s]*invz;
}

// ---------------- K5: out[b] = (sum_seg ctxp) . out_W + out_b ----------------
__global__ __launch_bounds__(512) void k5_out(const float* __restrict__ ctxp, const float* __restrict__ out_W,
                                              const float* __restrict__ out_b, float* __restrict__ out)
{
    __shared__ float red[8];
    const int b = blockIdx.x, c = threadIdx.x;
    const int dir = c >> 8, j = c & (HDIM-1);
    float acc = 0.f;
    #pragma unroll
    for (int seg=0; seg<SEG; ++seg)
        acc += ctxp[((size_t)(b*2+dir)*SEG + seg)*HDIM + j];
    float p = acc * out_W[c];
    #pragma unroll
    for (int o=32;o;o>>=1) p += __shfl_xor(p,o,64);
    if ((c&63)==0) red[c>>6] = p;
    __syncthreads();
    if (c==0){
        float t = 0.f;
        #pragma unroll
        for (int r=0;r<8;++r) t += red[r];
        out[b] = t + out_b[0];
    }
}

extern "C" void kernel_launch(void* const* d_in, const int* in_sizes, int n_in,
                              void* d_out, int out_size, void* d_ws, size_t ws_size,
                              hipStream_t stream)
{
    const float* X     = (const float*)d_in[0];
    const float* emb   = (const float*)d_in[1];
    const float* num_W = (const float*)d_in[2];
    const float* num_b = (const float*)d_in[3];
    const float* Wf    = (const float*)d_in[4];
    const float* bf    = (const float*)d_in[5];
    const float* Wb    = (const float*)d_in[6];
    const float* bb    = (const float*)d_in[7];
    const float* Mu    = (const float*)d_in[8];
    const float* out_W = (const float*)d_in[9];
    const float* out_b = (const float*)d_in[10];
    float* out = (float*)d_out;

    float* ws = (float*)d_ws;
    size_t off = 0;
    float* swp   = ws + off; off += (size_t)BN*8*SN;           // 4 MB
    float* w     = ws + off; off += (size_t)BN*SN;             // 0.5 MB
    float* T     = ws + off; off += (size_t)2*VOCABN*TWOH;     // interleaved, pre-scaled
    float* U     = ws + off; off += (size_t)2*8*TWOH;          // interleaved, pre-scaled
    float* aArr  = ws + off; off += (size_t)BN*2*SEG*HDIM;     // 2 MB
    float* cArr  = ws + off; off += (size_t)BN*2*SEG*HDIM;     // 2 MB
    float* hstart= ws + off; off += (size_t)BN*2*SEG*HDIM;     // 2 MB
    float* ctxp  = ws + off; off += (size_t)BN*2*SEG*HDIM;     // 2 MB
    float* Xp    = ws + off; off += (size_t)BN*SN*8;           // 4 MB prepacked X

    hipLaunchKernelGGL(k0_prep,     dim3(BN*SN/256),   dim3(256), 0, stream, X, Xp);
    hipLaunchKernelGGL(k1_tables,   dim3(2*VOCABN+2),  dim3(512), 0, stream,
                       emb, num_W, num_b, Wf, bf, Wb, bb, T, U);
    hipLaunchKernelGGL(k2_scan<0>,  dim3(BN*2*SEG),    dim3(256), 0, stream,
                       Xp, T, U, Mu, w, hstart, aArr, cArr, swp, ctxp);
    hipLaunchKernelGGL(k_compose,   dim3(BN*2),        dim3(256), 0, stream,
                       aArr, cArr, hstart);
    hipLaunchKernelGGL(k2_scan<1>,  dim3(BN*2*SEG),    dim3(256), 0, stream,
                       Xp, T, U, Mu, w, hstart, aArr, cArr, swp, ctxp);
    hipLaunchKernelGGL(k3_softmax,  dim3(BN),          dim3(256), 0, stream,
                       swp, w);
    hipLaunchKernelGGL(k2_scan<2>,  dim3(BN*2*SEG),    dim3(256), 0, stream,
                       Xp, T, U, Mu, w, hstart, aArr, cArr, swp, ctxp);
    hipLaunchKernelGGL(k5_out,      dim3(BN),          dim3(512), 0, stream,
                       ctxp, out_W, out_b, out);
}

// Round 8
// 195.061 us; speedup vs baseline: 1.0921x; 1.0921x over previous
//
#include <hip/hip_runtime.h>
#include <stdint.h>

#define VOCABN 64
#define EMBN   128
#define HDIM   256
#define NUMIN  7
#define BN     64
#define SN     2048
#define TWOH   512
#define SEG    16
#define SEGLEN 128

#define CZ 2.8853900818f   // 2*log2(e)
#define CF 1.4426950409f   // log2(e)

__device__ __forceinline__ float rcpf(float x){ return __builtin_amdgcn_rcpf(x); }

__device__ __forceinline__ float fast_exp2(float x){
#if __has_builtin(__builtin_amdgcn_exp2f)
    return __builtin_amdgcn_exp2f(x);
#else
    return exp2f(x);
#endif
}

// v_pk_fma_f32 with src0 = SGPR pair, broadcasting its LO word to both lanes of the result
__device__ __forceinline__ float2 pk_fma_s_lo(uint64_t a, float2 b, float2 c){
    float2 d;
    asm("v_pk_fma_f32 %0, %1, %2, %3 op_sel_hi:[0,1,1]" : "=v"(d) : "s"(a), "v"(b), "v"(c));
    return d;
}
// v_pk_fma_f32 with src0 = SGPR pair, broadcasting its HI word
__device__ __forceinline__ float2 pk_fma_s_hi(uint64_t a, float2 b, float2 c){
    float2 d;
    asm("v_pk_fma_f32 %0, %1, %2, %3 op_sel:[1,0,0] op_sel_hi:[1,1,1]" : "=v"(d) : "s"(a), "v"(b), "v"(c));
    return d;
}

// pack two f32 -> two bf16 (RNE) in one dword: lo16 = bf16(a), hi16 = bf16(b)
__device__ __forceinline__ uint32_t cvt_pk_bf16(float a, float b){
    uint32_t r;
    asm("v_cvt_pk_bf16_f32 %0, %1, %2" : "=v"(r) : "v"(a), "v"(b));
    return r;
}

// 64-lane sum via DPP; result valid in lane 63.
__device__ __forceinline__ float waveRedDpp(float x){
    x += __int_as_float(__builtin_amdgcn_update_dpp(0, __float_as_int(x), 0x111, 0xf, 0xf, false)); // row_shr:1
    x += __int_as_float(__builtin_amdgcn_update_dpp(0, __float_as_int(x), 0x112, 0xf, 0xf, false)); // row_shr:2
    x += __int_as_float(__builtin_amdgcn_update_dpp(0, __float_as_int(x), 0x114, 0xf, 0xf, false)); // row_shr:4
    x += __int_as_float(__builtin_amdgcn_update_dpp(0, __float_as_int(x), 0x118, 0xf, 0xf, false)); // row_shr:8
    x += __int_as_float(__builtin_amdgcn_update_dpp(0, __float_as_int(x), 0x142, 0xa, 0xf, false)); // row_bcast:15
    x += __int_as_float(__builtin_amdgcn_update_dpp(0, __float_as_int(x), 0x143, 0xc, 0xf, false)); // row_bcast:31
    return x;
}

// ---------------- K0: prepack X rows for scalar loads ----------------
// X'[row] = [n0 n1 n2 n3 n4 n5 n6 evByteOffsetBits]
__global__ __launch_bounds__(256) void k0_prep(const float* __restrict__ X, float* __restrict__ Xp)
{
    const int r = blockIdx.x*256 + threadIdx.x;     // r < BN*SN
    const float4* src = (const float4*)(X + (size_t)r*8);
    const float4 a = src[0], b4 = src[1];
    float4* dst = (float4*)(Xp + (size_t)r*8);
    dst[0] = make_float4(a.y, a.z, a.w, b4.x);
    dst[1] = make_float4(b4.y, b4.z, b4.w, __int_as_float((int)a.x * (HDIM*8)));
}

// ---------------- K1: fold emb/bias/num path into INTERLEAVED, PRE-SCALED tables ----------------
// T[(dir,v,j)] = float2(CZ*z-col j, CF*f-col j); U likewise (so exp2 applies directly).
__global__ __launch_bounds__(512) void k1_tables(
    const float* __restrict__ emb, const float* __restrict__ num_W, const float* __restrict__ num_b,
    const float* __restrict__ Wf, const float* __restrict__ bf,
    const float* __restrict__ Wb, const float* __restrict__ bb,
    float* __restrict__ T, float* __restrict__ U)
{
    const int blk = blockIdx.x;
    const int c = threadIdx.x;
    const int j = c & (HDIM-1);
    const int g = c >> 8;               // 0 -> z gate, 1 -> f gate
    const int col = g*HDIM + j;
    const float gs = g ? CF : CZ;
    if (blk < 2*VOCABN) {
        const int dir = blk & 1, v = blk >> 1;
        const float* W    = dir ? Wb : Wf;
        const float* bias = dir ? bb : bf;
        float acc = bias[col];
        const float* e = emb + (size_t)v*EMBN;
        #pragma unroll 8
        for (int k=0;k<EMBN;++k) acc = fmaf(e[k], W[(size_t)k*768 + col], acc);
        #pragma unroll
        for (int m=0;m<4;++m)    acc = fmaf(num_b[m], W[(size_t)(EMBN+m)*768 + col], acc);
        T[(((size_t)dir*VOCABN + v)*HDIM + j)*2 + g] = acc * gs;
    } else {
        const int dir = blk - 2*VOCABN;
        const float* W = dir ? Wb : Wf;
        #pragma unroll
        for (int i=0;i<NUMIN;++i){
            float acc = 0.f;
            #pragma unroll
            for (int m=0;m<4;++m) acc = fmaf(num_W[i*4+m], W[(size_t)(EMBN+m)*768 + col], acc);
            U[(((size_t)dir*8 + i)*HDIM + j)*2 + g] = acc * gs;
        }
    }
}

// ---------------- K2: segmented fo-pool scan (scalar-fed, LDS-free) ----------------
// MODE 0: per-segment affine coefficients a=prod(f), c=scan from 0.
// MODE 1: scan from hstart, score partials via DPP reduce, AND store h as packed bf16.
// MODE 2: scan from hstart, ctx += w[s]*h (recompute fallback, no h storage).
// MODE 3: scan from hstart, score partials only (fallback when h2 doesn't fit ws).
template<int MODE>
__global__ __launch_bounds__(256) void k2_scan(
    const float* __restrict__ Xp, const float* __restrict__ T, const float* __restrict__ U,
    const float* __restrict__ Mu, const float* __restrict__ w,
    const float* __restrict__ hstart,
    float* __restrict__ aArr, float* __restrict__ cArr,
    float* __restrict__ swp, float* __restrict__ ctxp, uint32_t* __restrict__ h2)
{
    const int bid = blockIdx.x;
    const int seg = bid & (SEG-1);
    const int dir = (bid >> 4) & 1;
    const int b   = bid >> 5;
    const int j   = threadIdx.x;
    const int blk = (b*2+dir)*SEG + seg;
    const size_t segIdx = (size_t)blk*HDIM + j;

    const float2* Td2 = (const float2*)T + (size_t)dir*VOCABN*HDIM;
    const float2* Ud2 = (const float2*)U + (size_t)dir*8*HDIM;
    float2 u0 = Ud2[0*HDIM+j], u1 = Ud2[1*HDIM+j], u2 = Ud2[2*HDIM+j],
           u3 = Ud2[3*HDIM+j], u4 = Ud2[4*HDIM+j], u5 = Ud2[5*HDIM+j],
           u6 = Ud2[6*HDIM+j];
    const float mu = (MODE==1 || MODE==3) ? Mu[dir*HDIM + j] : 0.f;

    const int sBeg = seg*SEGLEN;
    const int r0   = b*SN + (dir ? (SN-1-sBeg) : sBeg);
    const int dstep= dir ? -1 : 1;
    const uint64_t* xq = (const uint64_t*)Xp;      // 4 qwords per row
    const float* wb = w + (size_t)b*SN + sBeg;     // MODE2 weights (uniform loads)
    const char* Tb = (const char*)Td2;
    const int j8 = j*8;

    #define ROWQ(si,k) (xq[(size_t)(r0 + dstep*(si))*4 + (k)])

    // prologue: row 0 regs + 3-deep T prefetch ring
    uint64_t q0 = ROWQ(0,0), q1 = ROWQ(0,1), q2 = ROWQ(0,2), q3 = ROWQ(0,3);
    float2 tc0 = *(const float2*)(Tb + (int)(q3>>32) + j8);
    float2 tc1 = *(const float2*)(Tb + (int)(ROWQ(1,3)>>32) + j8);
    float2 tc2 = *(const float2*)(Tb + (int)(ROWQ(2,3)>>32) + j8);

    float h = (MODE==0) ? 0.f : hstart[segIdx];
    float aacc = 1.f;
    float ctxacc = 0.f;
    float hprev = 0.f;
    float* swpp = swp + (size_t)(b*8 + dir*4 + (j>>6))*SN + sBeg;
    uint32_t* h2p = h2 + (size_t)blk*(SEGLEN/2)*HDIM + j;

    #pragma unroll 8
    for (int si=0; si<SEGLEN; ++si){
        // scalar prefetch: next row's qwords, and T-row address 3 steps ahead
        const int sn1 = (si+1 < SEGLEN) ? si+1 : SEGLEN-1;
        const uint64_t nq0 = ROWQ(sn1,0), nq1 = ROWQ(sn1,1),
                       nq2 = ROWQ(sn1,2), nq3 = ROWQ(sn1,3);
        const int pf = (si+3 < SEGLEN) ? si+3 : SEGLEN-1;
        const uint64_t pq3 = ROWQ(pf,3);
        const float2 t3 = *(const float2*)(Tb + (int)(pq3>>32) + j8);

        float2 zf = tc0;
        zf = pk_fma_s_lo(q0, u0, zf);   // n0
        zf = pk_fma_s_hi(q0, u1, zf);   // n1
        zf = pk_fma_s_lo(q1, u2, zf);   // n2
        zf = pk_fma_s_hi(q1, u3, zf);   // n3
        zf = pk_fma_s_lo(q2, u4, zf);   // n4
        zf = pk_fma_s_hi(q2, u5, zf);   // n5
        zf = pk_fma_s_lo(q3, u6, zf);   // n6

        // gates via one reciprocal: zf = (CZ*zp, CF*fp) already scaled
        const float e2z = fast_exp2(zf.x);            // e^{2zp}
        const float ef  = fast_exp2(zf.y);            // e^{fp}
        const float a2  = 1.f + e2z;
        const float a1f = 1.f + ef;
        const float r_  = rcpf(a1f * a2);
        const float num = fmaf(ef * h, a2, e2z - 1.f);
        h = num * r_;

        if (MODE==0){
            aacc *= ef * a2 * r_;                     // f = ef/(1+ef)
        } else if (MODE==1 || MODE==3){
            float pr = waveRedDpp(h*mu);
            if ((j & 63) == 63) swpp[si] = pr;
            if (MODE==1){
                if (si & 1){ *h2p = cvt_pk_bf16(hprev, h); h2p += HDIM; }
                else hprev = h;
            }
        } else {
            ctxacc = fmaf(wb[si], h, ctxacc);
        }
        q0=nq0; q1=nq1; q2=nq2; q3=nq3;
        tc0=tc1; tc1=tc2; tc2=t3;
    }
    #undef ROWQ
    if (MODE==0){ aArr[segIdx] = aacc; cArr[segIdx] = h; }
    if (MODE==2){ ctxp[segIdx] = ctxacc; }
}

// ---------------- compose: hstart[seg] = h; h = a*h + c ----------------
__global__ __launch_bounds__(256) void k_compose(const float* __restrict__ aArr, const float* __restrict__ cArr,
                                                 float* __restrict__ hstart)
{
    const int bd = blockIdx.x;   // b*2 + dir
    const int j  = threadIdx.x;
    float h = 0.f;
    #pragma unroll
    for (int seg=0; seg<SEG; ++seg){
        const size_t idx = ((size_t)bd*SEG + seg)*HDIM + j;
        hstart[idx] = h;
        h = fmaf(aArr[idx], h, cArr[idx]);
    }
}

// ---------------- K3: softmax over S per batch ----------------
__global__ __launch_bounds__(256) void k3_softmax(const float* __restrict__ swp, float* __restrict__ w)
{
    __shared__ float sc[SN];
    __shared__ float red[4];
    const int b = blockIdx.x, t = threadIdx.x;
    for (int s=t; s<SN; s+=256){
        float acc = 0.f;
        #pragma unroll
        for (int r=0;r<8;++r) acc += swp[((size_t)b*8 + r)*SN + s];
        sc[s] = acc;
    }
    __syncthreads();
    float m = -3.4e38f;
    for (int s=t; s<SN; s+=256) m = fmaxf(m, sc[s]);
    #pragma unroll
    for (int o=32;o;o>>=1) m = fmaxf(m, __shfl_xor(m,o,64));
    if ((t&63)==0) red[t>>6] = m;
    __syncthreads();
    m = fmaxf(fmaxf(red[0],red[1]), fmaxf(red[2],red[3]));
    float zs = 0.f;
    for (int s=t; s<SN; s+=256){
        float e = __expf(sc[s]-m);
        sc[s] = e;
        zs += e;
    }
    #pragma unroll
    for (int o=32;o;o>>=1) zs += __shfl_xor(zs,o,64);
    __syncthreads();
    if ((t&63)==0) red[t>>6] = zs;
    __syncthreads();
    zs = red[0]+red[1]+red[2]+red[3];
    float invz = rcpf(zs);
    for (int s=t; s<SN; s+=256) w[(size_t)b*SN + s] = sc[s]*invz;
}

// ---------------- K4: ctx from stored bf16 h (memory-bound replay) ----------------
__global__ __launch_bounds__(256) void k4_ctx(const uint32_t* __restrict__ h2, const float* __restrict__ w,
                                              float* __restrict__ ctxp)
{
    const int bid = blockIdx.x;
    const int seg = bid & (SEG-1);
    const int dir = (bid >> 4) & 1;
    const int b   = bid >> 5;
    const int blk = (b*2+dir)*SEG + seg;
    const int j   = threadIdx.x;
    const float* wb = w + (size_t)b*SN + seg*SEGLEN;
    const uint32_t* hp = h2 + (size_t)blk*(SEGLEN/2)*HDIM + j;
    float acc = 0.f;
    #pragma unroll 8
    for (int si2=0; si2<SEGLEN/2; ++si2){
        const uint32_t pk = hp[(size_t)si2*HDIM];
        const float hlo = __int_as_float(pk << 16);
        const float hhi = __int_as_float(pk & 0xffff0000u);
        acc = fmaf(wb[2*si2  ], hlo, acc);
        acc = fmaf(wb[2*si2+1], hhi, acc);
    }
    ctxp[(size_t)blk*HDIM + j] = acc;
}

// ---------------- K5: out[b] = (sum_seg ctxp) . out_W + out_b ----------------
__global__ __launch_bounds__(512) void k5_out(const float* __restrict__ ctxp, const float* __restrict__ out_W,
                                              const float* __restrict__ out_b, float* __restrict__ out)
{
    __shared__ float red[8];
    const int b = blockIdx.x, c = threadIdx.x;
    const int dir = c >> 8, j = c & (HDIM-1);
    float acc = 0.f;
    #pragma unroll
    for (int seg=0; seg<SEG; ++seg)
        acc += ctxp[((size_t)(b*2+dir)*SEG + seg)*HDIM + j];
    float p = acc * out_W[c];
    #pragma unroll
    for (int o=32;o;o>>=1) p += __shfl_xor(p,o,64);
    if ((c&63)==0) red[c>>6] = p;
    __syncthreads();
    if (c==0){
        float t = 0.f;
        #pragma unroll
        for (int r=0;r<8;++r) t += red[r];
        out[b] = t + out_b[0];
    }
}

extern "C" void kernel_launch(void* const* d_in, const int* in_sizes, int n_in,
                              void* d_out, int out_size, void* d_ws, size_t ws_size,
                              hipStream_t stream)
{
    const float* X     = (const float*)d_in[0];
    const float* emb   = (const float*)d_in[1];
    const float* num_W = (const float*)d_in[2];
    const float* num_b = (const float*)d_in[3];
    const float* Wf    = (const float*)d_in[4];
    const float* bf    = (const float*)d_in[5];
    const float* Wb    = (const float*)d_in[6];
    const float* bb    = (const float*)d_in[7];
    const float* Mu    = (const float*)d_in[8];
    const float* out_W = (const float*)d_in[9];
    const float* out_b = (const float*)d_in[10];
    float* out = (float*)d_out;

    float* ws = (float*)d_ws;
    size_t off = 0;
    float* swp   = ws + off; off += (size_t)BN*8*SN;           // 4 MB
    float* w     = ws + off; off += (size_t)BN*SN;             // 0.5 MB
    float* T     = ws + off; off += (size_t)2*VOCABN*TWOH;     // interleaved, pre-scaled
    float* U     = ws + off; off += (size_t)2*8*TWOH;          // interleaved, pre-scaled
    float* aArr  = ws + off; off += (size_t)BN*2*SEG*HDIM;     // 2 MB
    float* cArr  = ws + off; off += (size_t)BN*2*SEG*HDIM;     // 2 MB
    float* hstart= ws + off; off += (size_t)BN*2*SEG*HDIM;     // 2 MB
    float* ctxp  = ws + off; off += (size_t)BN*2*SEG*HDIM;     // 2 MB
    float* Xp    = ws + off; off += (size_t)BN*SN*8;           // 4 MB prepacked X
    uint32_t* h2 = (uint32_t*)(ws + off);
    off += (size_t)BN*2*SEG*(SEGLEN/2)*HDIM;                   // 128 MB packed bf16 h
    const bool useStore = ((size_t)off * sizeof(float)) <= ws_size;

    hipLaunchKernelGGL(k0_prep,     dim3(BN*SN/256),   dim3(256), 0, stream, X, Xp);
    hipLaunchKernelGGL(k1_tables,   dim3(2*VOCABN+2),  dim3(512), 0, stream,
                       emb, num_W, num_b, Wf, bf, Wb, bb, T, U);
    hipLaunchKernelGGL(k2_scan<0>,  dim3(BN*2*SEG),    dim3(256), 0, stream,
                       Xp, T, U, Mu, w, hstart, aArr, cArr, swp, ctxp, h2);
    hipLaunchKernelGGL(k_compose,   dim3(BN*2),        dim3(256), 0, stream,
                       aArr, cArr, hstart);
    if (useStore) {
        hipLaunchKernelGGL(k2_scan<1>, dim3(BN*2*SEG), dim3(256), 0, stream,
                           Xp, T, U, Mu, w, hstart, aArr, cArr, swp, ctxp, h2);
        hipLaunchKernelGGL(k3_softmax, dim3(BN),       dim3(256), 0, stream, swp, w);
        hipLaunchKernelGGL(k4_ctx,     dim3(BN*2*SEG), dim3(256), 0, stream, h2, w, ctxp);
    } else {
        hipLaunchKernelGGL(k2_scan<3>, dim3(BN*2*SEG), dim3(256), 0, stream,
                           Xp, T, U, Mu, w, hstart, aArr, cArr, swp, ctxp, h2);
        hipLaunchKernelGGL(k3_softmax, dim3(BN),       dim3(256), 0, stream, swp, w);
        hipLaunchKernelGGL(k2_scan<2>, dim3(BN*2*SEG), dim3(256), 0, stream,
                           Xp, T, U, Mu, w, hstart, aArr, cArr, swp, ctxp, h2);
    }
    hipLaunchKernelGGL(k5_out,      dim3(BN),          dim3(512), 0, stream,
                       ctxp, out_W, out_b, out);
}

// Round 9
// 160.762 us; speedup vs baseline: 1.3251x; 1.2134x over previous
//
#include <hip/hip_runtime.h>
#include <stdint.h>

#define VOCABN 64
#define EMBN   128
#define HDIM   256
#define NUMIN  7
#define BN     64
#define SN     2048
#define TWOH   512
#define SEG    16
#define SEGLEN 128

#define CZ 2.8853900818f   // 2*log2(e)
#define CF 1.4426950409f   // log2(e)

__device__ __forceinline__ float rcpf(float x){ return __builtin_amdgcn_rcpf(x); }

__device__ __forceinline__ float fast_exp2(float x){
#if __has_builtin(__builtin_amdgcn_exp2f)
    return __builtin_amdgcn_exp2f(x);
#else
    return exp2f(x);
#endif
}

// v_pk_fma_f32 with src0 = SGPR pair, broadcasting its LO word to both lanes of the result
__device__ __forceinline__ float2 pk_fma_s_lo(uint64_t a, float2 b, float2 c){
    float2 d;
    asm("v_pk_fma_f32 %0, %1, %2, %3 op_sel_hi:[0,1,1]" : "=v"(d) : "s"(a), "v"(b), "v"(c));
    return d;
}
// v_pk_fma_f32 with src0 = SGPR pair, broadcasting its HI word
__device__ __forceinline__ float2 pk_fma_s_hi(uint64_t a, float2 b, float2 c){
    float2 d;
    asm("v_pk_fma_f32 %0, %1, %2, %3 op_sel:[1,0,0] op_sel_hi:[1,1,1]" : "=v"(d) : "s"(a), "v"(b), "v"(c));
    return d;
}

// pack two f32 -> two bf16 (RNE) in one dword: lo16 = bf16(a), hi16 = bf16(b)
__device__ __forceinline__ uint32_t cvt_pk_bf16(float a, float b){
    uint32_t r;
    asm("v_cvt_pk_bf16_f32 %0, %1, %2" : "=v"(r) : "v"(a), "v"(b));
    return r;
}

// 64-lane sum via DPP; result valid in lane 63.
__device__ __forceinline__ float waveRedDpp(float x){
    x += __int_as_float(__builtin_amdgcn_update_dpp(0, __float_as_int(x), 0x111, 0xf, 0xf, false)); // row_shr:1
    x += __int_as_float(__builtin_amdgcn_update_dpp(0, __float_as_int(x), 0x112, 0xf, 0xf, false)); // row_shr:2
    x += __int_as_float(__builtin_amdgcn_update_dpp(0, __float_as_int(x), 0x114, 0xf, 0xf, false)); // row_shr:4
    x += __int_as_float(__builtin_amdgcn_update_dpp(0, __float_as_int(x), 0x118, 0xf, 0xf, false)); // row_shr:8
    x += __int_as_float(__builtin_amdgcn_update_dpp(0, __float_as_int(x), 0x142, 0xa, 0xf, false)); // row_bcast:15
    x += __int_as_float(__builtin_amdgcn_update_dpp(0, __float_as_int(x), 0x143, 0xc, 0xf, false)); // row_bcast:31
    return x;
}

// ---------------- K0: prepack X rows for scalar loads ----------------
// X'[row] = [n0 n1 n2 n3 n4 n5 n6 evByteOffsetBits]
__global__ __launch_bounds__(256) void k0_prep(const float* __restrict__ X, float* __restrict__ Xp)
{
    const int r = blockIdx.x*256 + threadIdx.x;     // r < BN*SN
    const float4* src = (const float4*)(X + (size_t)r*8);
    const float4 a = src[0], b4 = src[1];
    float4* dst = (float4*)(Xp + (size_t)r*8);
    dst[0] = make_float4(a.y, a.z, a.w, b4.x);
    dst[1] = make_float4(b4.y, b4.z, b4.w, __int_as_float((int)a.x * (HDIM*8)));
}

// ---------------- K1: fold emb/bias/num path into INTERLEAVED, PRE-SCALED tables ----------------
// T[(dir,v,j)] = float2(CZ*z-col j, CF*f-col j); U likewise (so exp2 applies directly).
__global__ __launch_bounds__(512) void k1_tables(
    const float* __restrict__ emb, const float* __restrict__ num_W, const float* __restrict__ num_b,
    const float* __restrict__ Wf, const float* __restrict__ bf,
    const float* __restrict__ Wb, const float* __restrict__ bb,
    float* __restrict__ T, float* __restrict__ U)
{
    const int blk = blockIdx.x;
    const int c = threadIdx.x;
    const int j = c & (HDIM-1);
    const int g = c >> 8;               // 0 -> z gate, 1 -> f gate
    const int col = g*HDIM + j;
    const float gs = g ? CF : CZ;
    if (blk < 2*VOCABN) {
        const int dir = blk & 1, v = blk >> 1;
        const float* W    = dir ? Wb : Wf;
        const float* bias = dir ? bb : bf;
        float acc = bias[col];
        const float* e = emb + (size_t)v*EMBN;
        #pragma unroll 8
        for (int k=0;k<EMBN;++k) acc = fmaf(e[k], W[(size_t)k*768 + col], acc);
        #pragma unroll
        for (int m=0;m<4;++m)    acc = fmaf(num_b[m], W[(size_t)(EMBN+m)*768 + col], acc);
        T[(((size_t)dir*VOCABN + v)*HDIM + j)*2 + g] = acc * gs;
    } else {
        const int dir = blk - 2*VOCABN;
        const float* W = dir ? Wb : Wf;
        #pragma unroll
        for (int i=0;i<NUMIN;++i){
            float acc = 0.f;
            #pragma unroll
            for (int m=0;m<4;++m) acc = fmaf(num_W[i*4+m], W[(size_t)(EMBN+m)*768 + col], acc);
            U[(((size_t)dir*8 + i)*HDIM + j)*2 + g] = acc * gs;
        }
    }
}

// ---------------- K2: segmented fo-pool scan, 2 channels/thread ----------------
// MODE 0: per-segment affine coefficients a=prod(f), c=scan from 0.
// MODE 1: scan from hstart, score partials via DPP reduce, AND store h as packed bf16.
// MODE 2: scan from hstart, ctx += w[s]*h (recompute fallback, no h storage).
// MODE 3: scan from hstart, score partials only (fallback when h2 doesn't fit ws).
// Block=(b,dir,seg) with 128 threads; thread j owns channels j and j+128.
// X rows: depth-4 SGPR ring (scalar loads); T rows: depth-2 register ring, both
// channels' loads share one scalar base (saddr) with +1KB immediate.
template<int MODE>
__global__ __launch_bounds__(128) void k2_scan(
    const float* __restrict__ Xp, const float* __restrict__ T, const float* __restrict__ U,
    const float* __restrict__ Mu, const float* __restrict__ w,
    const float* __restrict__ hstart,
    float* __restrict__ aArr, float* __restrict__ cArr,
    float* __restrict__ swp, float* __restrict__ ctxp, uint32_t* __restrict__ h2)
{
    const int bid = blockIdx.x;
    const int seg = bid & (SEG-1);
    const int dir = (bid >> 4) & 1;
    const int b   = bid >> 5;
    const int j   = threadIdx.x;            // 0..127
    const int blk = (b*2+dir)*SEG + seg;
    const size_t segIdx = (size_t)blk*HDIM + j;   // channel j; +128 for hi channel

    const float2* Td2 = (const float2*)T + (size_t)dir*VOCABN*HDIM;
    const float2* Ud2 = (const float2*)U + (size_t)dir*8*HDIM;
    float2 uLo0=Ud2[0*HDIM+j],     uLo1=Ud2[1*HDIM+j],     uLo2=Ud2[2*HDIM+j],
           uLo3=Ud2[3*HDIM+j],     uLo4=Ud2[4*HDIM+j],     uLo5=Ud2[5*HDIM+j],
           uLo6=Ud2[6*HDIM+j];
    float2 uHi0=Ud2[0*HDIM+j+128], uHi1=Ud2[1*HDIM+j+128], uHi2=Ud2[2*HDIM+j+128],
           uHi3=Ud2[3*HDIM+j+128], uHi4=Ud2[4*HDIM+j+128], uHi5=Ud2[5*HDIM+j+128],
           uHi6=Ud2[6*HDIM+j+128];
    const float muLo = (MODE==1 || MODE==3) ? Mu[dir*HDIM + j]       : 0.f;
    const float muHi = (MODE==1 || MODE==3) ? Mu[dir*HDIM + j + 128] : 0.f;

    const int sBeg = seg*SEGLEN;
    const int r0   = b*SN + (dir ? (SN-1-sBeg) : sBeg);
    const int dstep= dir ? -1 : 1;
    const uint64_t* xq = (const uint64_t*)Xp;      // 4 qwords per row
    const float* wb = w + (size_t)b*SN + sBeg;     // MODE2 weights (uniform loads)
    const char* Tb = (const char*)Td2;
    const int j8 = j*8;

    #define ROWQ(si,k) (xq[(size_t)(r0 + dstep*(si))*4 + (k)])
    #define TROW(q)    (Tb + (int)((q)>>32))

    // prologue: X ring depth 4, T ring depth 2 (both channels)
    uint64_t qa0=ROWQ(0,0), qa1=ROWQ(0,1), qa2=ROWQ(0,2), qa3=ROWQ(0,3);
    uint64_t qb0=ROWQ(1,0), qb1=ROWQ(1,1), qb2=ROWQ(1,2), qb3=ROWQ(1,3);
    uint64_t qc0=ROWQ(2,0), qc1=ROWQ(2,1), qc2=ROWQ(2,2), qc3=ROWQ(2,3);
    uint64_t qd0=ROWQ(3,0), qd1=ROWQ(3,1), qd2=ROWQ(3,2), qd3=ROWQ(3,3);
    const char* tp0 = TROW(qa3);
    const char* tp1 = TROW(qb3);
    float2 tLo0 = *(const float2*)(tp0 + j8);
    float2 tHi0 = *(const float2*)(tp0 + j8 + 1024);
    float2 tLo1 = *(const float2*)(tp1 + j8);
    float2 tHi1 = *(const float2*)(tp1 + j8 + 1024);

    float hLo = (MODE==0) ? 0.f : hstart[segIdx];
    float hHi = (MODE==0) ? 0.f : hstart[segIdx + 128];
    float aaccLo = 1.f, aaccHi = 1.f;
    float ctxLo = 0.f, ctxHi = 0.f;
    float hpLo = 0.f, hpHi = 0.f;
    float* swpp = swp + (size_t)(b*4 + dir*2 + (j>>6))*SN + sBeg;
    uint32_t* h2p = h2 + (size_t)blk*(SEGLEN/2)*HDIM + j;

    #pragma unroll 4
    for (int si=0; si<SEGLEN; ++si){
        // issue X scalar loads for si+4 (2-iter slack before use as T base, 4 before math)
        const int i4 = (si+4 < SEGLEN) ? si+4 : SEGLEN-1;
        const uint64_t qe0=ROWQ(i4,0), qe1=ROWQ(i4,1), qe2=ROWQ(i4,2), qe3=ROWQ(i4,3);
        // issue T loads for si+2 (base from qc, loaded 2 iterations ago)
        const char* tp2 = TROW(qc3);
        const float2 tLo2 = *(const float2*)(tp2 + j8);
        const float2 tHi2 = *(const float2*)(tp2 + j8 + 1024);

        float2 zfLo = tLo0, zfHi = tHi0;
        zfLo = pk_fma_s_lo(qa0, uLo0, zfLo);  zfHi = pk_fma_s_lo(qa0, uHi0, zfHi);  // n0
        zfLo = pk_fma_s_hi(qa0, uLo1, zfLo);  zfHi = pk_fma_s_hi(qa0, uHi1, zfHi);  // n1
        zfLo = pk_fma_s_lo(qa1, uLo2, zfLo);  zfHi = pk_fma_s_lo(qa1, uHi2, zfHi);  // n2
        zfLo = pk_fma_s_hi(qa1, uLo3, zfLo);  zfHi = pk_fma_s_hi(qa1, uHi3, zfHi);  // n3
        zfLo = pk_fma_s_lo(qa2, uLo4, zfLo);  zfHi = pk_fma_s_lo(qa2, uHi4, zfHi);  // n4
        zfLo = pk_fma_s_hi(qa2, uLo5, zfLo);  zfHi = pk_fma_s_hi(qa2, uHi5, zfHi);  // n5
        zfLo = pk_fma_s_lo(qa3, uLo6, zfLo);  zfHi = pk_fma_s_lo(qa3, uHi6, zfHi);  // n6

        // gates, one reciprocal per channel (zf pre-scaled by CZ/CF)
        const float e2zL = fast_exp2(zfLo.x), efL = fast_exp2(zfLo.y);
        const float e2zH = fast_exp2(zfHi.x), efH = fast_exp2(zfHi.y);
        const float a2L = 1.f + e2zL, a1L = 1.f + efL;
        const float a2H = 1.f + e2zH, a1H = 1.f + efH;
        const float rL = rcpf(a1L * a2L);
        const float rH = rcpf(a1H * a2H);
        hLo = fmaf(efL * hLo, a2L, e2zL - 1.f) * rL;
        hHi = fmaf(efH * hHi, a2H, e2zH - 1.f) * rH;

        if (MODE==0){
            aaccLo *= efL * a2L * rL;            // f = ef/(1+ef)
            aaccHi *= efH * a2H * rH;
        } else if (MODE==1 || MODE==3){
            float pr = waveRedDpp(fmaf(hHi, muHi, hLo * muLo));
            if ((j & 63) == 63) swpp[si] = pr;
            if (MODE==1){
                if (si & 1){
                    h2p[0]   = cvt_pk_bf16(hpLo, hLo);
                    h2p[128] = cvt_pk_bf16(hpHi, hHi);
                    h2p += HDIM;
                } else { hpLo = hLo; hpHi = hHi; }
            }
        } else {
            const float ws_ = wb[si];
            ctxLo = fmaf(ws_, hLo, ctxLo);
            ctxHi = fmaf(ws_, hHi, ctxHi);
        }
        // rotate rings
        qa0=qb0; qa1=qb1; qa2=qb2; qa3=qb3;
        qb0=qc0; qb1=qc1; qb2=qc2; qb3=qc3;
        qc0=qd0; qc1=qd1; qc2=qd2; qc3=qd3;
        qd0=qe0; qd1=qe1; qd2=qe2; qd3=qe3;
        tLo0=tLo1; tHi0=tHi1; tLo1=tLo2; tHi1=tHi2;
    }
    #undef ROWQ
    #undef TROW
    if (MODE==0){
        aArr[segIdx] = aaccLo; aArr[segIdx+128] = aaccHi;
        cArr[segIdx] = hLo;    cArr[segIdx+128] = hHi;
    }
    if (MODE==2){ ctxp[segIdx] = ctxLo; ctxp[segIdx+128] = ctxHi; }
}

// ---------------- compose: hstart[seg] = h; h = a*h + c ----------------
__global__ __launch_bounds__(256) void k_compose(const float* __restrict__ aArr, const float* __restrict__ cArr,
                                                 float* __restrict__ hstart)
{
    const int bd = blockIdx.x;   // b*2 + dir
    const int j  = threadIdx.x;
    float h = 0.f;
    #pragma unroll
    for (int seg=0; seg<SEG; ++seg){
        const size_t idx = ((size_t)bd*SEG + seg)*HDIM + j;
        hstart[idx] = h;
        h = fmaf(aArr[idx], h, cArr[idx]);
    }
}

// ---------------- K3: softmax over S per batch (4 partial rows per b) ----------------
__global__ __launch_bounds__(256) void k3_softmax(const float* __restrict__ swp, float* __restrict__ w)
{
    __shared__ float sc[SN];
    __shared__ float red[4];
    const int b = blockIdx.x, t = threadIdx.x;
    for (int s=t; s<SN; s+=256){
        float acc = 0.f;
        #pragma unroll
        for (int r=0;r<4;++r) acc += swp[((size_t)b*4 + r)*SN + s];
        sc[s] = acc;
    }
    __syncthreads();
    float m = -3.4e38f;
    for (int s=t; s<SN; s+=256) m = fmaxf(m, sc[s]);
    #pragma unroll
    for (int o=32;o;o>>=1) m = fmaxf(m, __shfl_xor(m,o,64));
    if ((t&63)==0) red[t>>6] = m;
    __syncthreads();
    m = fmaxf(fmaxf(red[0],red[1]), fmaxf(red[2],red[3]));
    float zs = 0.f;
    for (int s=t; s<SN; s+=256){
        float e = __expf(sc[s]-m);
        sc[s] = e;
        zs += e;
    }
    #pragma unroll
    for (int o=32;o;o>>=1) zs += __shfl_xor(zs,o,64);
    __syncthreads();
    if ((t&63)==0) red[t>>6] = zs;
    __syncthreads();
    zs = red[0]+red[1]+red[2]+red[3];
    float invz = rcpf(zs);
    for (int s=t; s<SN; s+=256) w[(size_t)b*SN + s] = sc[s]*invz;
}

// ---------------- K4: ctx from stored bf16 h (memory-bound replay) ----------------
__global__ __launch_bounds__(256) void k4_ctx(const uint32_t* __restrict__ h2, const float* __restrict__ w,
                                              float* __restrict__ ctxp)
{
    const int bid = blockIdx.x;
    const int seg = bid & (SEG-1);
    const int dir = (bid >> 4) & 1;
    const int b   = bid >> 5;
    const int blk = (b*2+dir)*SEG + seg;
    const int j   = threadIdx.x;
    const float* wb = w + (size_t)b*SN + seg*SEGLEN;
    const uint32_t* hp = h2 + (size_t)blk*(SEGLEN/2)*HDIM + j;
    float acc = 0.f;
    #pragma unroll 8
    for (int si2=0; si2<SEGLEN/2; ++si2){
        const uint32_t pk = hp[(size_t)si2*HDIM];
        const float hlo = __int_as_float(pk << 16);
        const float hhi = __int_as_float(pk & 0xffff0000u);
        acc = fmaf(wb[2*si2  ], hlo, acc);
        acc = fmaf(wb[2*si2+1], hhi, acc);
    }
    ctxp[(size_t)blk*HDIM + j] = acc;
}

// ---------------- K5: out[b] = (sum_seg ctxp) . out_W + out_b ----------------
__global__ __launch_bounds__(512) void k5_out(const float* __restrict__ ctxp, const float* __restrict__ out_W,
                                              const float* __restrict__ out_b, float* __restrict__ out)
{
    __shared__ float red[8];
    const int b = blockIdx.x, c = threadIdx.x;
    const int dir = c >> 8, j = c & (HDIM-1);
    float acc = 0.f;
    #pragma unroll
    for (int seg=0; seg<SEG; ++seg)
        acc += ctxp[((size_t)(b*2+dir)*SEG + seg)*HDIM + j];
    float p = acc * out_W[c];
    #pragma unroll
    for (int o=32;o;o>>=1) p += __shfl_xor(p,o,64);
    if ((c&63)==0) red[c>>6] = p;
    __syncthreads();
    if (c==0){
        float t = 0.f;
        #pragma unroll
        for (int r=0;r<8;++r) t += red[r];
        out[b] = t + out_b[0];
    }
}

extern "C" void kernel_launch(void* const* d_in, const int* in_sizes, int n_in,
                              void* d_out, int out_size, void* d_ws, size_t ws_size,
                              hipStream_t stream)
{
    const float* X     = (const float*)d_in[0];
    const float* emb   = (const float*)d_in[1];
    const float* num_W = (const float*)d_in[2];
    const float* num_b = (const float*)d_in[3];
    const float* Wf    = (const float*)d_in[4];
    const float* bf    = (const float*)d_in[5];
    const float* Wb    = (const float*)d_in[6];
    const float* bb    = (const float*)d_in[7];
    const float* Mu    = (const float*)d_in[8];
    const float* out_W = (const float*)d_in[9];
    const float* out_b = (const float*)d_in[10];
    float* out = (float*)d_out;

    float* ws = (float*)d_ws;
    size_t off = 0;
    float* swp   = ws + off; off += (size_t)BN*4*SN;           // 2 MB (4 partial rows per b)
    float* w     = ws + off; off += (size_t)BN*SN;             // 0.5 MB
    float* T     = ws + off; off += (size_t)2*VOCABN*TWOH;     // interleaved, pre-scaled
    float* U     = ws + off; off += (size_t)2*8*TWOH;          // interleaved, pre-scaled
    float* aArr  = ws + off; off += (size_t)BN*2*SEG*HDIM;     // 2 MB
    float* cArr  = ws + off; off += (size_t)BN*2*SEG*HDIM;     // 2 MB
    float* hstart= ws + off; off += (size_t)BN*2*SEG*HDIM;     // 2 MB
    float* ctxp  = ws + off; off += (size_t)BN*2*SEG*HDIM;     // 2 MB
    float* Xp    = ws + off; off += (size_t)BN*SN*8;           // 4 MB prepacked X
    uint32_t* h2 = (uint32_t*)(ws + off);
    off += (size_t)BN*2*SEG*(SEGLEN/2)*HDIM;                   // 128 MB packed bf16 h
    const bool useStore = ((size_t)off * sizeof(float)) <= ws_size;

    hipLaunchKernelGGL(k0_prep,     dim3(BN*SN/256),   dim3(256), 0, stream, X, Xp);
    hipLaunchKernelGGL(k1_tables,   dim3(2*VOCABN+2),  dim3(512), 0, stream,
                       emb, num_W, num_b, Wf, bf, Wb, bb, T, U);
    hipLaunchKernelGGL(k2_scan<0>,  dim3(BN*2*SEG),    dim3(128), 0, stream,
                       Xp, T, U, Mu, w, hstart, aArr, cArr, swp, ctxp, h2);
    hipLaunchKernelGGL(k_compose,   dim3(BN*2),        dim3(256), 0, stream,
                       aArr, cArr, hstart);
    if (useStore) {
        hipLaunchKernelGGL(k2_scan<1>, dim3(BN*2*SEG), dim3(128), 0, stream,
                           Xp, T, U, Mu, w, hstart, aArr, cArr, swp, ctxp, h2);
        hipLaunchKernelGGL(k3_softmax, dim3(BN),       dim3(256), 0, stream, swp, w);
        hipLaunchKernelGGL(k4_ctx,     dim3(BN*2*SEG), dim3(256), 0, stream, h2, w, ctxp);
    } else {
        hipLaunchKernelGGL(k2_scan<3>, dim3(BN*2*SEG), dim3(128), 0, stream,
                           Xp, T, U, Mu, w, hstart, aArr, cArr, swp, ctxp, h2);
        hipLaunchKernelGGL(k3_softmax, dim3(BN),       dim3(256), 0, stream, swp, w);
        hipLaunchKernelGGL(k2_scan<2>, dim3(BN*2*SEG), dim3(128), 0, stream,
                           Xp, T, U, Mu, w, hstart, aArr, cArr, swp, ctxp, h2);
    }
    hipLaunchKernelGGL(k5_out,      dim3(BN),          dim3(512), 0, stream,
                       ctxp, out_W, out_b, out);
}